// Round 23
// baseline (78.407 us; speedup 1.0000x reference)
//
#include <hip/hip_runtime.h>

// VQ nearest-codebook argmin — fp16 MFMA pass-1 (code-split, 4 waves/SIMD,
// __syncthreads template) + block-per-row rescore.
//
// Pass 1 (math validated r8-r22): G ≈ z16 . fp16(1024 e)/1024, one f16 MFMA
//   pass; rows with top-2 gap <= TAU=1.6e-4 -> list.
//   r23 = r21's code-split structure (16 rows x 512 codes per wave, 32-row
//   blocks, grid 1024 = 4 blocks/CU = 4 waves/SIMD — 2x TLP of r22) on the
//   r22-proven __syncthreads sync template (r21's raw-barrier triplet raced:
//   compiler hoisted ds_reads past the asm barrier; __syncthreads is
//   compiler-ordered and passed the determinism tripwire in r22).
// Pass 2 (validated r13-r22, absmax 0 + tripwire-clean): block per flagged
//   row; coalesced fp16 dot2 scan; candidates v <= bv + WIN=1.2e-4; LOCKED
//   numpy-fp32 recipe per candidate (rounds 3-22): s1,s2 numpy-pairwise fp32
//   sums of squares; G exact-fp64 (order-free) -> fl32(2G);
//   d = fl32(fl32(s1-2G)+s2); argmin, first-index tie-break.

#define DDIM 256
#define KCODES 1024
#define TAU 1.6e-4f
#define WIN 1.2e-4f
#define LISTCAP 16384
#define CANDCAP 16
#define P2GRID 2048

typedef __attribute__((ext_vector_type(8))) _Float16 f16x8;
typedef __attribute__((ext_vector_type(2))) _Float16 h2;
typedef __attribute__((ext_vector_type(4))) float f32x4;
typedef __attribute__((ext_vector_type(8))) unsigned short u16x8;

// ---------- locked numerics helper (rounds 3-22, do not touch) ----------
__device__ __forceinline__ float block128_sq(const float* __restrict__ a)
{
#pragma clang fp contract(off)
    float r[8];
    #pragma unroll
    for (int j = 0; j < 8; ++j) { float v = a[j]; r[j] = v * v; }
    #pragma unroll
    for (int i = 8; i < 128; i += 8) {
        #pragma unroll
        for (int j = 0; j < 8; ++j) { float v = a[i + j]; r[j] = r[j] + v * v; }
    }
    return ((r[0] + r[1]) + (r[2] + r[3])) + ((r[4] + r[5]) + (r[6] + r[7]));
}

// ---- prep: e16 = fp16(1024*e), s2 pairwise, count reset (r9-validated) ----
__global__ __launch_bounds__(256) void vq_prep(
    const float* __restrict__ emb, unsigned short* __restrict__ e16,
    float* __restrict__ s2, int* __restrict__ count)
{
    const int tid = threadIdx.x;
    if (blockIdx.x == 0 && tid == 0) *count = 0;

    const int id = blockIdx.x * 256 + tid;
    const float* src = emb + (size_t)id * 8;
    float4 p0 = *reinterpret_cast<const float4*>(src);
    float4 p1 = *reinterpret_cast<const float4*>(src + 4);
    float fv[8] = {p0.x, p0.y, p0.z, p0.w, p1.x, p1.y, p1.z, p1.w};
    u16x8 vh;
    #pragma unroll
    for (int e = 0; e < 8; ++e) {
        _Float16 h = (_Float16)(fv[e] * 1024.0f);
        vh[e] = __builtin_bit_cast(unsigned short, h);
    }
    *reinterpret_cast<u16x8*>(e16 + (size_t)id * 8) = vh;

    if (tid < 8) {
        const int c = blockIdx.x * 8 + tid;
        const float* e = emb + (size_t)c * DDIM;
        s2[c] = block128_sq(e) + block128_sq(e + 128);
    }
}

// ---- pass 1 (fp16 MFMA, code-split: 16 rows x 512 codes per wave) ----
__global__ __launch_bounds__(256, 4) void vq_pass1(
    const float* __restrict__ z, const unsigned short* __restrict__ e16,
    const float* __restrict__ s2g, int* __restrict__ out,
    int* __restrict__ count, int* __restrict__ list, int N)
{
    // Bt[buf]: [half][128 codes][32 halfs] — r8-validated 0-conflict layout
    __shared__ __align__(16) unsigned short Bt[2][8192];    // 32 KB
    __shared__ float s2s[KCODES];                           //  4 KB
    __shared__ float Lbv[2][32], Lsv[2][32];
    __shared__ int   Lbk[2][32];

    const int tid  = threadIdx.x;
    const int wid  = tid >> 6, lane = tid & 63;
    const int ll   = lane & 15, lg = lane >> 4;
    const int rowHalf  = wid & 1, codeHalf = wid >> 1;
    const int rowbase  = blockIdx.x * 32 + rowHalf * 16;    // 16 rows per wave
    const int chbase   = codeHalf * 512;

    for (int c = tid; c < KCODES; c += 256) s2s[c] = s2g[c];

    const int sB     = (ll >> 1) & 3;
    const int rdbase = ll * 32 + ((lg ^ sB) << 3);

    // A fragments, whole K, converted once (STATIC indices — r17 spill fix)
    f16x8 afrag[8];
    #pragma unroll
    for (int ks = 0; ks < 8; ++ks) {
        const float* zp = z + (size_t)(rowbase + ll) * DDIM + ks * 32 + lg * 8;
        float4 p0 = *reinterpret_cast<const float4*>(zp);
        float4 p1 = *reinterpret_cast<const float4*>(zp + 4);
        float fv[8] = {p0.x, p0.y, p0.z, p0.w, p1.x, p1.y, p1.z, p1.w};
        #pragma unroll
        for (int e = 0; e < 8; ++e) afrag[ks][e] = (_Float16)fv[e];
    }

    // STAGE tile nt (both code-halves, 128 codes each, 32 k): 16KB, 4 chunks/thr
    #define STAGE(nt_, buf_)                                                      \
        {                                                                         \
            const int nt_v = (nt_);                                               \
            _Pragma("unroll")                                                     \
            for (int q = 0; q < 4; ++q) {                                         \
                int id = q * 256 + tid;                                           \
                int half = id >> 9, rem = id & 511, cl = rem >> 2, pc = rem & 3;  \
                int clog = pc ^ ((cl >> 1) & 3);                                  \
                const unsigned short* src = e16 +                                 \
                    (size_t)(half * 512 + (nt_v >> 3) * 128 + cl) * DDIM          \
                        + (nt_v & 7) * 32 + clog * 8;                             \
                __builtin_amdgcn_global_load_lds(                                 \
                    (const __attribute__((address_space(1))) void*)src,           \
                    (__attribute__((address_space(3))) void*)&Bt[buf_][(size_t)id * 8], \
                    16, 0, 0);                                                    \
            }                                                                     \
        }

    float bv[4], sv[4];
    int   bk[4];
    #pragma unroll
    for (int j = 0; j < 4; ++j) { bv[j] = 3.4e38f; sv[j] = 3.4e38f; bk[j] = 0; }

    STAGE(0, 0);

    for (int ct = 0; ct < 4; ++ct) {
        f32x4 acc[8];
        const f32x4 zero4 = {0.f, 0.f, 0.f, 0.f};
        #pragma unroll
        for (int n = 0; n < 8; ++n) acc[n] = zero4;

        #pragma unroll
        for (int ks = 0; ks < 8; ++ks) {               // ks STATIC -> regs
            const int t = ct * 8 + ks;
            __syncthreads();        // compiler-ordered full drain + barrier:
                                    // tile t staged; buf^1 free to overwrite

            if (t < 31) STAGE(t + 1, (t + 1) & 1);     // hide under compute

            const unsigned short* bbase = &Bt[t & 1][codeHalf * 4096];
            #pragma unroll
            for (int n = 0; n < 8; ++n) {
                f16x8 bh = *reinterpret_cast<const f16x8*>(bbase + n * 512 + rdbase);
                acc[n] = __builtin_amdgcn_mfma_f32_16x16x32_f16(
                    afrag[ks], bh, acc[n], 0, 0, 0);
            }
        }

        // fold ct into running top-2 (validated formula/order)
        #pragma unroll
        for (int n = 0; n < 8; ++n) {
            const int c = chbase + ct * 128 + n * 16 + ll;
            const float s2v = s2s[c];
            #pragma unroll
            for (int j = 0; j < 4; ++j) {
                float v = fmaf(-0.001953125f, acc[n][j], s2v);
                if (v < bv[j] || (v == bv[j] && c < bk[j])) {
                    sv[j] = bv[j]; bv[j] = v; bk[j] = c;
                } else {
                    sv[j] = fminf(sv[j], v);
                }
            }
        }
    }
    #undef STAGE

    // reduce over the 16 ll-lanes (xor 1,2,4,8 keeps lg fixed)
    #pragma unroll
    for (int off = 1; off < 16; off <<= 1) {
        #pragma unroll
        for (int j = 0; j < 4; ++j) {
            float ob = __shfl_xor(bv[j], off, 64);
            int   ok = __shfl_xor(bk[j], off, 64);
            float os = __shfl_xor(sv[j], off, 64);
            if (ob < bv[j] || (ob == bv[j] && ok < bk[j])) {
                sv[j] = fminf(bv[j], os); bv[j] = ob; bk[j] = ok;
            } else {
                sv[j] = fminf(sv[j], ob);
            }
        }
    }

    if (ll == 0) {
        #pragma unroll
        for (int j = 0; j < 4; ++j) {
            int rib = rowHalf * 16 + lg * 4 + j;            // C/D row map (locked)
            Lbv[codeHalf][rib] = bv[j];
            Lsv[codeHalf][rib] = sv[j];
            Lbk[codeHalf][rib] = bk[j];
        }
    }
    __syncthreads();

    // merge code-halves (half-0 indices < half-1 always; strict < keeps
    // first-index semantics) — r17/r22-validated pattern
    if (tid < 32) {
        const int r = blockIdx.x * 32 + tid;
        if (r < N) {
            float b0 = Lbv[0][tid], s0 = Lsv[0][tid]; int k0 = Lbk[0][tid];
            float b1 = Lbv[1][tid], s1 = Lsv[1][tid]; int k1 = Lbk[1][tid];
            float bb, ss; int kk;
            if (b1 < b0) { bb = b1; kk = k1; ss = fminf(s1, b0); }
            else         { bb = b0; kk = k0; ss = fminf(s0, b1); }
            out[r] = kk;
            if (ss - bb <= TAU) {
                int pos = atomicAdd(count, 1);
                if (pos < LISTCAP) list[pos] = r;
            }
        }
    }
}

// ------- pass 2: block-per-row fp16 scan + exact window (r15-r22 verbatim) -------
__global__ __launch_bounds__(256, 4) void vq_pass2(
    const float* __restrict__ z, const float* __restrict__ emb,
    const unsigned short* __restrict__ e16, const float* __restrict__ s2g,
    const int* __restrict__ count, const int* __restrict__ list,
    int* __restrict__ out)
{
#pragma clang fp contract(off)
    __shared__ __align__(16) float zls[DDIM];
    __shared__ float vls[KCODES];
    __shared__ float s2s[KCODES];
    __shared__ float s1sh, bvsh;
    __shared__ float wmin[4];
    __shared__ int   candc[CANDCAP];
    __shared__ float cand_v[CANDCAP];
    __shared__ int   ncand;

    const int tid  = threadIdx.x;
    const int wv   = tid >> 6, lane = tid & 63;
    const int cslot = lane >> 2;
    const int sub   = lane & 3;

    int cnt = *count; if (cnt > LISTCAP) cnt = LISTCAP;
    if ((int)blockIdx.x >= cnt) return;

    for (int c = tid; c < KCODES; c += 256) s2s[c] = s2g[c];

    for (int idx = blockIdx.x; idx < cnt; idx += P2GRID) {
        const int row = list[idx];

        if (tid < 64)
            *reinterpret_cast<float4*>(&zls[tid * 4]) =
                *reinterpret_cast<const float4*>(z + (size_t)row * DDIM + tid * 4);
        if (tid == 65) ncand = 0;
        __syncthreads();

        if (tid == 0) s1sh = block128_sq(zls) + block128_sq(zls + 128);

        h2 z16[32];
        {
            const float2* zp2 = reinterpret_cast<const float2*>(&zls[0]);
            #pragma unroll
            for (int q = 0; q < 8; ++q)
                #pragma unroll
                for (int j = 0; j < 4; ++j) {
                    float2 f = zp2[q * 16 + sub * 4 + j];
                    h2 a; a[0] = (_Float16)f.x; a[1] = (_Float16)f.y;
                    z16[q * 4 + j] = a;
                }
        }

        #pragma unroll 1
        for (int i = 0; i < 16; ++i) {
            const int c = wv * 256 + i * 16 + cslot;
            const unsigned short* base = e16 + (size_t)c * DDIM;

            float p = 0.f;
            #pragma unroll
            for (int h = 0; h < 2; ++h) {
                f16x8 e0 = *reinterpret_cast<const f16x8*>(base + (4 * h + 0) * 32 + sub * 8);
                f16x8 e1 = *reinterpret_cast<const f16x8*>(base + (4 * h + 1) * 32 + sub * 8);
                f16x8 e2 = *reinterpret_cast<const f16x8*>(base + (4 * h + 2) * 32 + sub * 8);
                f16x8 e3 = *reinterpret_cast<const f16x8*>(base + (4 * h + 3) * 32 + sub * 8);
                #pragma unroll
                for (int j = 0; j < 4; ++j) {
                    h2 a0; a0[0] = e0[2 * j]; a0[1] = e0[2 * j + 1];
                    h2 a1; a1[0] = e1[2 * j]; a1[1] = e1[2 * j + 1];
                    h2 a2; a2[0] = e2[2 * j]; a2[1] = e2[2 * j + 1];
                    h2 a3; a3[0] = e3[2 * j]; a3[1] = e3[2 * j + 1];
#if __has_builtin(__builtin_amdgcn_fdot2)
                    p = __builtin_amdgcn_fdot2(a0, z16[(4 * h + 0) * 4 + j], p, false);
                    p = __builtin_amdgcn_fdot2(a1, z16[(4 * h + 1) * 4 + j], p, false);
                    p = __builtin_amdgcn_fdot2(a2, z16[(4 * h + 2) * 4 + j], p, false);
                    p = __builtin_amdgcn_fdot2(a3, z16[(4 * h + 3) * 4 + j], p, false);
#else
                    p = fmaf((float)a0[0], (float)z16[(4 * h + 0) * 4 + j][0], p);
                    p = fmaf((float)a0[1], (float)z16[(4 * h + 0) * 4 + j][1], p);
                    p = fmaf((float)a1[0], (float)z16[(4 * h + 1) * 4 + j][0], p);
                    p = fmaf((float)a1[1], (float)z16[(4 * h + 1) * 4 + j][1], p);
                    p = fmaf((float)a2[0], (float)z16[(4 * h + 2) * 4 + j][0], p);
                    p = fmaf((float)a2[1], (float)z16[(4 * h + 2) * 4 + j][1], p);
                    p = fmaf((float)a3[0], (float)z16[(4 * h + 3) * 4 + j][0], p);
                    p = fmaf((float)a3[1], (float)z16[(4 * h + 3) * 4 + j][1], p);
#endif
                }
            }
            p += __shfl_xor(p, 1, 64);
            p += __shfl_xor(p, 2, 64);
            if (sub == 0)
                vls[c] = fmaf(-0.001953125f, p, s2s[c]);
        }
        __syncthreads();

        float m = 3.4e38f;
        #pragma unroll
        for (int k = 0; k < 4; ++k) m = fminf(m, vls[tid + 256 * k]);
        #pragma unroll
        for (int off = 1; off < 64; off <<= 1) m = fminf(m, __shfl_xor(m, off, 64));
        if (lane == 0) wmin[wv] = m;
        __syncthreads();
        if (tid == 0)
            bvsh = fminf(fminf(wmin[0], wmin[1]), fminf(wmin[2], wmin[3]));
        __syncthreads();

        const float thr = bvsh + WIN;
        #pragma unroll
        for (int k = 0; k < 4; ++k) {
            int c = tid + 256 * k;
            if (vls[c] <= thr) {
                int p = atomicAdd(&ncand, 1);
                if (p < CANDCAP) candc[p] = c;
            }
        }
        __syncthreads();
        int nc2 = ncand; if (nc2 > CANDCAP) nc2 = CANDCAP;
        const float s1 = s1sh;

        for (int i = wv; i < nc2; i += 4) {
            const int c = candc[i];
            float4 ev4 = *reinterpret_cast<const float4*>(emb + (size_t)c * DDIM + lane * 4);
            const float* zq = &zls[lane * 4];
            double ds = (double)zq[0] * (double)ev4.x;
            ds = fma((double)zq[1], (double)ev4.y, ds);
            ds = fma((double)zq[2], (double)ev4.z, ds);
            ds = fma((double)zq[3], (double)ev4.w, ds);
            #pragma unroll
            for (int off = 1; off < 64; off <<= 1)
                ds += __shfl_xor(ds, off, 64);
            if (lane == 0) {
                float twog = 2.0f * (float)ds;
                float t1   = s1 - twog;
                cand_v[i]  = t1 + s2s[c];
            }
        }
        __syncthreads();

        if (tid == 0) {
            float bb = 3.4e38f; int kb = KCODES - 1;
            for (int i = 0; i < nc2; ++i) {
                float dv = cand_v[i]; int c = candc[i];
                if (dv < bb || (dv == bb && c < kb)) { bb = dv; kb = c; }
            }
            out[row] = kb;
        }
        __syncthreads();
    }
}

extern "C" void kernel_launch(void* const* d_in, const int* in_sizes, int n_in,
                              void* d_out, int out_size, void* d_ws, size_t ws_size,
                              hipStream_t stream) {
    const float* z   = (const float*)d_in[0];
    const float* emb = (const float*)d_in[1];
    int*   out   = (int*)d_out;
    float* s2    = (float*)d_ws;                                   // 4 KB
    int*   count = (int*)((char*)d_ws + 4096);
    int*   list  = (int*)((char*)d_ws + 4224);                     // 64 KB
    unsigned short* e16 = (unsigned short*)((char*)d_ws + 131072); // 512 KB
    const int N = in_sizes[0] / DDIM;                              // 32768

    vq_prep<<<dim3(128), dim3(256), 0, stream>>>(emb, e16, s2, count);
    vq_pass1<<<dim3(N / 32), dim3(256), 0, stream>>>(z, e16, s2, out, count, list, N);
    vq_pass2<<<dim3(P2GRID), dim3(256), 0, stream>>>(z, emb, e16, s2, count, list, out);
}

// Round 24
// 72.851 us; speedup vs baseline: 1.0763x; 1.0763x over previous
//
#include <hip/hip_runtime.h>

// VQ nearest-codebook argmin — fp16 MFMA pass-1 (full-K tile, __syncthreads)
// + block-per-row rescore.  FINAL (r22 verbatim — best verified: 72.9us,
// absmax 0, determinism-tripwire clean).
//
// Pass 1 (math validated r8-r23): G ≈ z16 . fp16(1024 e)/1024, one f16 MFMA
//   pass; rows with top-2 gap <= TAU=1.6e-4 -> list. 512-thr blocks, 128
//   rows, full-K code-tile (128 codes x 256 K = 64KB) double-buffered, one
//   __syncthreads per code-tile (compiler-ordered vmcnt+lgkmcnt drain — the
//   race-free global_load_lds template; r21's raw-barrier variant raced).
//   Pass-1 ceiling evidence: 7 structural variants (r15-r23: BK, counted
//   vmcnt, sync-round count, linear staging, LDS-volume, 4 waves/SIMD) all
//   land at ~60us ≈ 290 TF — the m102 reference band for this shape class.
// Pass 2 (validated r13-r23, absmax 0): block per flagged row; coalesced fp16
//   dot2 scan; candidates v <= bv + WIN=1.2e-4; LOCKED numpy-fp32 recipe per
//   candidate (rounds 3-23): s1,s2 numpy-pairwise fp32 sums of squares;
//   G exact-fp64 (order-free) -> fl32(2G); d = fl32(fl32(s1-2G)+s2);
//   argmin, first-index tie-break.

#define DDIM 256
#define KCODES 1024
#define TAU 1.6e-4f
#define WIN 1.2e-4f
#define LISTCAP 16384
#define CANDCAP 16
#define P2GRID 2048

typedef __attribute__((ext_vector_type(8))) _Float16 f16x8;
typedef __attribute__((ext_vector_type(2))) _Float16 h2;
typedef __attribute__((ext_vector_type(4))) float f32x4;
typedef __attribute__((ext_vector_type(8))) unsigned short u16x8;

// ---------- locked numerics helper (rounds 3-23, do not touch) ----------
__device__ __forceinline__ float block128_sq(const float* __restrict__ a)
{
#pragma clang fp contract(off)
    float r[8];
    #pragma unroll
    for (int j = 0; j < 8; ++j) { float v = a[j]; r[j] = v * v; }
    #pragma unroll
    for (int i = 8; i < 128; i += 8) {
        #pragma unroll
        for (int j = 0; j < 8; ++j) { float v = a[i + j]; r[j] = r[j] + v * v; }
    }
    return ((r[0] + r[1]) + (r[2] + r[3])) + ((r[4] + r[5]) + (r[6] + r[7]));
}

// ---- prep: e16 = fp16(1024*e), s2 pairwise, count reset (r9-validated) ----
__global__ __launch_bounds__(256) void vq_prep(
    const float* __restrict__ emb, unsigned short* __restrict__ e16,
    float* __restrict__ s2, int* __restrict__ count)
{
    const int tid = threadIdx.x;
    if (blockIdx.x == 0 && tid == 0) *count = 0;

    const int id = blockIdx.x * 256 + tid;
    const float* src = emb + (size_t)id * 8;
    float4 p0 = *reinterpret_cast<const float4*>(src);
    float4 p1 = *reinterpret_cast<const float4*>(src + 4);
    float fv[8] = {p0.x, p0.y, p0.z, p0.w, p1.x, p1.y, p1.z, p1.w};
    u16x8 vh;
    #pragma unroll
    for (int e = 0; e < 8; ++e) {
        _Float16 h = (_Float16)(fv[e] * 1024.0f);
        vh[e] = __builtin_bit_cast(unsigned short, h);
    }
    *reinterpret_cast<u16x8*>(e16 + (size_t)id * 8) = vh;

    if (tid < 8) {
        const int c = blockIdx.x * 8 + tid;
        const float* e = emb + (size_t)c * DDIM;
        s2[c] = block128_sq(e) + block128_sq(e + 128);
    }
}

// ---- pass 1 (fp16 MFMA, full-K tile, __syncthreads per code-tile) ----
__global__ __launch_bounds__(512, 2) void vq_pass1(
    const float* __restrict__ z, const unsigned short* __restrict__ e16,
    const float* __restrict__ s2g, int* __restrict__ out,
    int* __restrict__ count, int* __restrict__ list, int N)
{
    // Bt[buf]: one code-tile = 8 slabs (ks) of the r8-validated 0-conflict
    // [128 codes][32 halfs] layout; slab ks at halfs-offset ks*4096.
    __shared__ __align__(16) unsigned short Bt[2][32768];   // 128 KB
    __shared__ float s2s[KCODES];                           //   4 KB

    const int tid  = threadIdx.x;
    const int wid  = tid >> 6, lane = tid & 63;
    const int ll   = lane & 15, lg = lane >> 4;
    const int rowbase = blockIdx.x * 128 + wid * 16;        // 16 rows per wave

    for (int c = tid; c < KCODES; c += 512) s2s[c] = s2g[c];

    const int sB     = (ll >> 1) & 3;
    const int rdbase = ll * 32 + ((lg ^ sB) << 3);

    // A fragments, whole K, converted once (STATIC indices — r17 spill fix)
    f16x8 afrag[8];
    #pragma unroll
    for (int ks = 0; ks < 8; ++ks) {
        const float* zp = z + (size_t)(rowbase + ll) * DDIM + ks * 32 + lg * 8;
        float4 p0 = *reinterpret_cast<const float4*>(zp);
        float4 p1 = *reinterpret_cast<const float4*>(zp + 4);
        float fv[8] = {p0.x, p0.y, p0.z, p0.w, p1.x, p1.y, p1.z, p1.w};
        #pragma unroll
        for (int e = 0; e < 8; ++e) afrag[ks][e] = (_Float16)fv[e];
    }

    // stage code-tile ct (128 codes x full K) via global_load_lds:
    // id = q*512+tid in [0,4096); ks=id>>9, cl=(id&511)>>2, pc=id&3;
    // LDS dest = id*16B (linear: wave-uniform + lane*16); swizzle on source.
    #define STAGE(ct_, buf_)                                                      \
        {                                                                         \
            const int ct_v = (ct_);                                               \
            _Pragma("unroll")                                                     \
            for (int q = 0; q < 8; ++q) {                                         \
                int id = q * 512 + tid;                                           \
                int ks = id >> 9, rem = id & 511, cl = rem >> 2, pc = rem & 3;    \
                int clog = pc ^ ((cl >> 1) & 3);                                  \
                const unsigned short* src = e16 +                                 \
                    (size_t)(ct_v * 128 + cl) * DDIM + ks * 32 + clog * 8;        \
                __builtin_amdgcn_global_load_lds(                                 \
                    (const __attribute__((address_space(1))) void*)src,           \
                    (__attribute__((address_space(3))) void*)&Bt[buf_][(size_t)id * 8], \
                    16, 0, 0);                                                    \
            }                                                                     \
        }

    float bv[4], sv[4];
    int   bk[4];
    #pragma unroll
    for (int j = 0; j < 4; ++j) { bv[j] = 3.4e38f; sv[j] = 3.4e38f; bk[j] = 0; }

    STAGE(0, 0);

    for (int ct = 0; ct < 8; ++ct) {
        const int buf = ct & 1;
        __syncthreads();            // full drain (vmcnt+lgkmcnt) + barrier:
                                    // tile ct staged, buf^1 free to overwrite

        if (ct < 7) STAGE(ct + 1, buf ^ 1);                 // hide under compute

        f32x4 acc[8];
        const f32x4 zero4 = {0.f, 0.f, 0.f, 0.f};
        #pragma unroll
        for (int n = 0; n < 8; ++n) acc[n] = zero4;

        #pragma unroll
        for (int ks = 0; ks < 8; ++ks) {                    // STATIC -> regs
            #pragma unroll
            for (int n = 0; n < 8; ++n) {
                f16x8 bh = *reinterpret_cast<const f16x8*>(
                    &Bt[buf][ks * 4096 + n * 512 + rdbase]);
                acc[n] = __builtin_amdgcn_mfma_f32_16x16x32_f16(
                    afrag[ks], bh, acc[n], 0, 0, 0);
            }
        }

        // fold ct into running top-2 (validated formula/order)
        #pragma unroll
        for (int n = 0; n < 8; ++n) {
            const int c = ct * 128 + n * 16 + ll;
            const float s2v = s2s[c];
            #pragma unroll
            for (int j = 0; j < 4; ++j) {
                float v = fmaf(-0.001953125f, acc[n][j], s2v);
                if (v < bv[j] || (v == bv[j] && c < bk[j])) {
                    sv[j] = bv[j]; bv[j] = v; bk[j] = c;
                } else {
                    sv[j] = fminf(sv[j], v);
                }
            }
        }
    }
    #undef STAGE

    // reduce over the 16 ll-lanes (xor 1,2,4,8 keeps lg fixed) — each wave
    // saw all 1024 codes, so no cross-wave merge needed.
    #pragma unroll
    for (int off = 1; off < 16; off <<= 1) {
        #pragma unroll
        for (int j = 0; j < 4; ++j) {
            float ob = __shfl_xor(bv[j], off, 64);
            int   ok = __shfl_xor(bk[j], off, 64);
            float os = __shfl_xor(sv[j], off, 64);
            if (ob < bv[j] || (ob == bv[j] && ok < bk[j])) {
                sv[j] = fminf(bv[j], os); bv[j] = ob; bk[j] = ok;
            } else {
                sv[j] = fminf(sv[j], ob);
            }
        }
    }

    if (ll == 0) {
        #pragma unroll
        for (int j = 0; j < 4; ++j) {
            int r = rowbase + lg * 4 + j;                   // C/D row map (locked)
            if (r < N) {
                out[r] = bk[j];
                if (sv[j] - bv[j] <= TAU) {
                    int pos = atomicAdd(count, 1);
                    if (pos < LISTCAP) list[pos] = r;
                }
            }
        }
    }
}

// ------- pass 2: block-per-row fp16 scan + exact window (r15-r23 verbatim) -------
__global__ __launch_bounds__(256, 4) void vq_pass2(
    const float* __restrict__ z, const float* __restrict__ emb,
    const unsigned short* __restrict__ e16, const float* __restrict__ s2g,
    const int* __restrict__ count, const int* __restrict__ list,
    int* __restrict__ out)
{
#pragma clang fp contract(off)
    __shared__ __align__(16) float zls[DDIM];
    __shared__ float vls[KCODES];
    __shared__ float s2s[KCODES];
    __shared__ float s1sh, bvsh;
    __shared__ float wmin[4];
    __shared__ int   candc[CANDCAP];
    __shared__ float cand_v[CANDCAP];
    __shared__ int   ncand;

    const int tid  = threadIdx.x;
    const int wv   = tid >> 6, lane = tid & 63;
    const int cslot = lane >> 2;
    const int sub   = lane & 3;

    int cnt = *count; if (cnt > LISTCAP) cnt = LISTCAP;
    if ((int)blockIdx.x >= cnt) return;

    for (int c = tid; c < KCODES; c += 256) s2s[c] = s2g[c];

    for (int idx = blockIdx.x; idx < cnt; idx += P2GRID) {
        const int row = list[idx];

        if (tid < 64)
            *reinterpret_cast<float4*>(&zls[tid * 4]) =
                *reinterpret_cast<const float4*>(z + (size_t)row * DDIM + tid * 4);
        if (tid == 65) ncand = 0;
        __syncthreads();

        if (tid == 0) s1sh = block128_sq(zls) + block128_sq(zls + 128);

        h2 z16[32];
        {
            const float2* zp2 = reinterpret_cast<const float2*>(&zls[0]);
            #pragma unroll
            for (int q = 0; q < 8; ++q)
                #pragma unroll
                for (int j = 0; j < 4; ++j) {
                    float2 f = zp2[q * 16 + sub * 4 + j];
                    h2 a; a[0] = (_Float16)f.x; a[1] = (_Float16)f.y;
                    z16[q * 4 + j] = a;
                }
        }

        #pragma unroll 1
        for (int i = 0; i < 16; ++i) {
            const int c = wv * 256 + i * 16 + cslot;
            const unsigned short* base = e16 + (size_t)c * DDIM;

            float p = 0.f;
            #pragma unroll
            for (int h = 0; h < 2; ++h) {
                f16x8 e0 = *reinterpret_cast<const f16x8*>(base + (4 * h + 0) * 32 + sub * 8);
                f16x8 e1 = *reinterpret_cast<const f16x8*>(base + (4 * h + 1) * 32 + sub * 8);
                f16x8 e2 = *reinterpret_cast<const f16x8*>(base + (4 * h + 2) * 32 + sub * 8);
                f16x8 e3 = *reinterpret_cast<const f16x8*>(base + (4 * h + 3) * 32 + sub * 8);
                #pragma unroll
                for (int j = 0; j < 4; ++j) {
                    h2 a0; a0[0] = e0[2 * j]; a0[1] = e0[2 * j + 1];
                    h2 a1; a1[0] = e1[2 * j]; a1[1] = e1[2 * j + 1];
                    h2 a2; a2[0] = e2[2 * j]; a2[1] = e2[2 * j + 1];
                    h2 a3; a3[0] = e3[2 * j]; a3[1] = e3[2 * j + 1];
#if __has_builtin(__builtin_amdgcn_fdot2)
                    p = __builtin_amdgcn_fdot2(a0, z16[(4 * h + 0) * 4 + j], p, false);
                    p = __builtin_amdgcn_fdot2(a1, z16[(4 * h + 1) * 4 + j], p, false);
                    p = __builtin_amdgcn_fdot2(a2, z16[(4 * h + 2) * 4 + j], p, false);
                    p = __builtin_amdgcn_fdot2(a3, z16[(4 * h + 3) * 4 + j], p, false);
#else
                    p = fmaf((float)a0[0], (float)z16[(4 * h + 0) * 4 + j][0], p);
                    p = fmaf((float)a0[1], (float)z16[(4 * h + 0) * 4 + j][1], p);
                    p = fmaf((float)a1[0], (float)z16[(4 * h + 1) * 4 + j][0], p);
                    p = fmaf((float)a1[1], (float)z16[(4 * h + 1) * 4 + j][1], p);
                    p = fmaf((float)a2[0], (float)z16[(4 * h + 2) * 4 + j][0], p);
                    p = fmaf((float)a2[1], (float)z16[(4 * h + 2) * 4 + j][1], p);
                    p = fmaf((float)a3[0], (float)z16[(4 * h + 3) * 4 + j][0], p);
                    p = fmaf((float)a3[1], (float)z16[(4 * h + 3) * 4 + j][1], p);
#endif
                }
            }
            p += __shfl_xor(p, 1, 64);
            p += __shfl_xor(p, 2, 64);
            if (sub == 0)
                vls[c] = fmaf(-0.001953125f, p, s2s[c]);
        }
        __syncthreads();

        float m = 3.4e38f;
        #pragma unroll
        for (int k = 0; k < 4; ++k) m = fminf(m, vls[tid + 256 * k]);
        #pragma unroll
        for (int off = 1; off < 64; off <<= 1) m = fminf(m, __shfl_xor(m, off, 64));
        if (lane == 0) wmin[wv] = m;
        __syncthreads();
        if (tid == 0)
            bvsh = fminf(fminf(wmin[0], wmin[1]), fminf(wmin[2], wmin[3]));
        __syncthreads();

        const float thr = bvsh + WIN;
        #pragma unroll
        for (int k = 0; k < 4; ++k) {
            int c = tid + 256 * k;
            if (vls[c] <= thr) {
                int p = atomicAdd(&ncand, 1);
                if (p < CANDCAP) candc[p] = c;
            }
        }
        __syncthreads();
        int nc2 = ncand; if (nc2 > CANDCAP) nc2 = CANDCAP;
        const float s1 = s1sh;

        for (int i = wv; i < nc2; i += 4) {
            const int c = candc[i];
            float4 ev4 = *reinterpret_cast<const float4*>(emb + (size_t)c * DDIM + lane * 4);
            const float* zq = &zls[lane * 4];
            double ds = (double)zq[0] * (double)ev4.x;
            ds = fma((double)zq[1], (double)ev4.y, ds);
            ds = fma((double)zq[2], (double)ev4.z, ds);
            ds = fma((double)zq[3], (double)ev4.w, ds);
            #pragma unroll
            for (int off = 1; off < 64; off <<= 1)
                ds += __shfl_xor(ds, off, 64);
            if (lane == 0) {
                float twog = 2.0f * (float)ds;
                float t1   = s1 - twog;
                cand_v[i]  = t1 + s2s[c];
            }
        }
        __syncthreads();

        if (tid == 0) {
            float bb = 3.4e38f; int kb = KCODES - 1;
            for (int i = 0; i < nc2; ++i) {
                float dv = cand_v[i]; int c = candc[i];
                if (dv < bb || (dv == bb && c < kb)) { bb = dv; kb = c; }
            }
            out[row] = kb;
        }
        __syncthreads();
    }
}

extern "C" void kernel_launch(void* const* d_in, const int* in_sizes, int n_in,
                              void* d_out, int out_size, void* d_ws, size_t ws_size,
                              hipStream_t stream) {
    const float* z   = (const float*)d_in[0];
    const float* emb = (const float*)d_in[1];
    int*   out   = (int*)d_out;
    float* s2    = (float*)d_ws;                                   // 4 KB
    int*   count = (int*)((char*)d_ws + 4096);
    int*   list  = (int*)((char*)d_ws + 4224);                     // 64 KB
    unsigned short* e16 = (unsigned short*)((char*)d_ws + 131072); // 512 KB
    const int N = in_sizes[0] / DDIM;                              // 32768

    vq_prep<<<dim3(128), dim3(256), 0, stream>>>(emb, e16, s2, count);
    vq_pass1<<<dim3(N / 128), dim3(512), 0, stream>>>(z, e16, s2, out, count, list, N);
    vq_pass2<<<dim3(P2GRID), dim3(256), 0, stream>>>(z, emb, e16, s2, count, list, out);
}